// Round 4
// baseline (547.420 us; speedup 1.0000x reference)
//
#include <hip/hip_runtime.h>
#include <hip/hip_bf16.h>

// CellAnnotator fused kernel: att (8x8 spatially-varying local conv as per-tile MFMA GEMM)
// + 4x (64x64 MLP + relu + LayerNorm) + 64->1 head, all in one persistent kernel.
// Precision: every f32 operand split hi/lo bf16 (hi+lo ~ 16 mantissa bits); GEMMs run
// hi@hi + hi@lo + lo@hi accumulating in fp32 -> near-fp32 accuracy on bf16 MFMA pipe.
// Occupancy: 256 blocks (1/CU, LDS 148KB), each loops 36 tiles; weights staged once.

#define HH 768
#define WW 768
#define CC 64
#define HWPX (HH*WW)
#define NTILES 9216           // (768/8)*(768/8)

typedef __attribute__((ext_vector_type(8))) short short8;
typedef __attribute__((ext_vector_type(4))) float f32x4;

__device__ __forceinline__ ushort f2bf(float f) {
  union { float f; uint u; } c; c.f = f;
  uint u = c.u;
  uint r = u + 0x7fffu + ((u >> 16) & 1u);   // round-to-nearest-even
  return (ushort)(r >> 16);
}
__device__ __forceinline__ float bf2f(ushort h) {
  union { uint u; float f; } c; c.u = ((uint)h) << 16;
  return c.f;
}
__device__ __forceinline__ float sigmoidf(float v) {
  return 1.f / (1.f + __expf(-v));
}

// pitch-224 row (28 groups of 8 ushorts). XOR-swizzle restricted to the LOW 2 BITS of the
// group index so every 4-group block stays in-bounds (bijective; max pos 27 < 28).
// R3 bug: XOR on 3 bits sent g in [24,28) to positions up to 31 -> wrote past the row.
// Reads (16 lanes, consecutive rows, fixed g) land 2-way on banks (free, m136).
__device__ __forceinline__ int swz224(int row, int g) {
  const int key = ((row & 7) ^ ((row >> 3) & 7)) & 3;
  return row * 224 + (((g & ~3) | ((g & 3) ^ key)) << 3);
}
// wt: pitch 64, full 3-bit swizzle keyed by co&7 (8 groups per row -> bijective)
__device__ __forceinline__ int wtoff(int plane, int layer, int co, int g) {
  return plane * 16384 + (((layer << 6) + co) << 6) + (((g ^ (co & 7)) & 7) << 3) + ((g & ~7) << 3);
}

__global__ __launch_bounds__(256, 1)
void fused_cell(const float* __restrict__ x, const float* __restrict__ Ws,
                const float* __restrict__ bs, const float* __restrict__ lns,
                const float* __restrict__ lnb, const float* __restrict__ w_out,
                const float* __restrict__ b_out, float* __restrict__ x0_out,
                float* __restrict__ out1) {
  __shared__ __align__(16) ushort wt[2 * 4 * 64 * 64];  // 64 KB: [plane hi/lo][layer][co][ci swz]
  __shared__ __align__(16) ushort Mh[64 * 224];         // 28 KB: M (hi then lo); act overlay later
  __shared__ __align__(16) ushort Xh[64 * 224];         // 28 KB
  __shared__ __align__(16) ushort Xl[64 * 224];         // 28 KB   total 148 KB

  const int tid = threadIdx.x;
  const int lane = tid & 63, w = tid >> 6;
  const int l15 = lane & 15, lg = lane >> 4;
  const int c4 = (tid & 15) << 2;          // channel quad this thread owns in center loads

  // ---- stage wt hi/lo once (thread (l,ci) reads Ws[l][ci][:] coalesced) ----
  {
    const int l = tid >> 6, ci = tid & 63;
    const float* src = Ws + (((l << 6) + ci) << 6);
    #pragma unroll
    for (int q = 0; q < 16; ++q) {
      const float4 v = *reinterpret_cast<const float4*>(src + q * 4);
      const float vs[4] = {v.x, v.y, v.z, v.w};
      #pragma unroll
      for (int j = 0; j < 4; ++j) {
        const int co = q * 4 + j;
        const int off = (((l << 6) + co) << 6) + ((((ci >> 3) ^ (co & 7)) << 3) | (ci & 7));
        const ushort h = f2bf(vs[j]);
        wt[off] = h;
        wt[16384 + off] = f2bf(vs[j] - bf2f(h));
      }
    }
  }

  // ---- hoist per-lane params ----
  float bias[4][4], sc[4][4], lbv[4][4];
  #pragma unroll
  for (int L = 0; L < 4; ++L)
    #pragma unroll
    for (int nb = 0; nb < 4; ++nb) {
      const int ch = (L << 6) + nb * 16 + l15;
      bias[L][nb] = bs[ch]; sc[L][nb] = lns[ch]; lbv[L][nb] = lnb[ch];
    }
  float wo[4];
  #pragma unroll
  for (int nb = 0; nb < 4; ++nb) wo[nb] = w_out[nb * 16 + l15];
  const float b0s = b_out[0];
  __syncthreads();

  for (int tile = blockIdx.x; tile < NTILES; tile += gridDim.x) {
    const int ti = (tile / (WW / 8)) * 8;
    const int tj = (tile % (WW / 8)) * 8;

    __syncthreads();                       // S0: prior tile done with M/X regions

    // ---- zero M ----
    #pragma unroll
    for (int i = 0; i < 7; ++i)
      *reinterpret_cast<uint4*>(&Mh[(tid + i * 256) * 8]) = make_uint4(0u, 0u, 0u, 0u);

    // ---- center-pixel loads + sigmoid (retained in regs for both scatters) ----
    float sv[16];
    #pragma unroll
    for (int i = 0; i < 4; ++i) {
      const int p = (tid >> 4) + 16 * i;   // pixel 0..63
      const int pr = p >> 3, pc = p & 7;
      const float4 v = *reinterpret_cast<const float4*>(
          x + ((size_t)((ti + pr) * WW + (tj + pc)) << 6) + c4);
      sv[i * 4 + 0] = sigmoidf(v.x);
      sv[i * 4 + 1] = sigmoidf(v.y);
      sv[i * 4 + 2] = sigmoidf(v.z);
      sv[i * 4 + 3] = sigmoidf(v.w);
    }

    // ---- stage X^T hi+lo (lane = channel, 8 halo px per group, coalesced 256B loads) ----
    #pragma unroll
    for (int t = 0; t < 7; ++t) {
      const int gi = w + 4 * t;            // k-group 0..27
      float vvx[8];
      #pragma unroll
      for (int s = 0; s < 8; ++s) {
        const int q = gi * 8 + s;
        const int gr = ti + q / 15 - 3, gc = tj + q % 15 - 3;
        vvx[s] = ((unsigned)gr < (unsigned)HH && (unsigned)gc < (unsigned)WW)
                     ? x[((size_t)(gr * WW + gc) << 6) + lane] : 0.f;
      }
      short8 h8, l8;
      #pragma unroll
      for (int s = 0; s < 8; ++s) {
        const ushort h = f2bf(vvx[s]);
        h8[s] = (short)h;
        l8[s] = (short)f2bf(vvx[s] - bf2f(h));
      }
      const int off = swz224(lane, gi);
      *reinterpret_cast<short8*>(&Xh[off]) = h8;
      *reinterpret_cast<short8*>(&Xl[off]) = l8;
    }
    __syncthreads();                       // S1: M zeroed (+X staged)

    // ---- scatter M hi ----
    #pragma unroll
    for (int i = 0; i < 4; ++i) {
      const int p = (tid >> 4) + 16 * i;
      const int pr = p >> 3, pc = p & 7;
      #pragma unroll
      for (int j = 0; j < 4; ++j) {
        const int k = c4 + j;
        const int q = (pr + (k >> 3)) * 15 + pc + (k & 7);
        if (q < 224) Mh[swz224(p, q >> 3) + (q & 7)] = f2bf(sv[i * 4 + j]);
      }
    }
    __syncthreads();                       // S2: Mhi + X visible

    // ---- GEMM P1 (Mhi@Xhi, retain A-frags) + P2 (Mhi@Xlo) ----
    const int arow = w * 16 + l15;
    short8 afr[7];
    f32x4 acc[4];
    #pragma unroll
    for (int nb = 0; nb < 4; ++nb) acc[nb] = {0.f, 0.f, 0.f, 0.f};
    #pragma unroll
    for (int ks = 0; ks < 7; ++ks) {
      const int g = ks * 4 + lg;
      afr[ks] = *reinterpret_cast<const short8*>(&Mh[swz224(arow, g)]);
      #pragma unroll
      for (int nb = 0; nb < 4; ++nb) {
        const short8 b = *reinterpret_cast<const short8*>(&Xh[swz224(nb * 16 + l15, g)]);
        acc[nb] = __builtin_amdgcn_mfma_f32_16x16x32_bf16(afr[ks], b, acc[nb], 0, 0, 0);
      }
    }
    #pragma unroll
    for (int ks = 0; ks < 7; ++ks) {
      const int g = ks * 4 + lg;
      #pragma unroll
      for (int nb = 0; nb < 4; ++nb) {
        const short8 b = *reinterpret_cast<const short8*>(&Xl[swz224(nb * 16 + l15, g)]);
        acc[nb] = __builtin_amdgcn_mfma_f32_16x16x32_bf16(afr[ks], b, acc[nb], 0, 0, 0);
      }
    }
    __syncthreads();                       // S3: all P1/P2 A-reads of Mhi done

    // ---- scatter M lo (same slots; rest stays zero) ----
    #pragma unroll
    for (int i = 0; i < 4; ++i) {
      const int p = (tid >> 4) + 16 * i;
      const int pr = p >> 3, pc = p & 7;
      #pragma unroll
      for (int j = 0; j < 4; ++j) {
        const int k = c4 + j;
        const int q = (pr + (k >> 3)) * 15 + pc + (k & 7);
        if (q < 224) {
          const float s = sv[i * 4 + j];
          Mh[swz224(p, q >> 3) + (q & 7)] = f2bf(s - bf2f(f2bf(s)));
        }
      }
    }
    __syncthreads();                       // S4: Mlo visible

    // ---- GEMM P3 (Mlo@Xhi) ----
    #pragma unroll
    for (int ks = 0; ks < 7; ++ks) {
      const int g = ks * 4 + lg;
      const short8 a = *reinterpret_cast<const short8*>(&Mh[swz224(arow, g)]);
      #pragma unroll
      for (int nb = 0; nb < 4; ++nb) {
        const short8 b = *reinterpret_cast<const short8*>(&Xh[swz224(nb * 16 + l15, g)]);
        acc[nb] = __builtin_amdgcn_mfma_f32_16x16x32_bf16(a, b, acc[nb], 0, 0, 0);
      }
    }

    // ---- fixup: halo px 224 (global (ti+11,tj+11)) contributes only to out px 63 ----
    if (w == 3 && lg == 3 && ti + 11 < HH && tj + 11 < WW) {
      const float xc = x[((size_t)((ti + 7) * WW + (tj + 7)) << 6) + 63];
      const float w63 = sigmoidf(xc);
      const size_t bp = ((size_t)((ti + 11) * WW + (tj + 11)) << 6);
      #pragma unroll
      for (int nb = 0; nb < 4; ++nb)
        acc[nb][3] += w63 * x[bp + nb * 16 + l15];
    }

    // ---- MLP: act scratch overlays this wave's private M rows (7168 B/wave) ----
    ushort* const actw = ((ushort*)Mh) + w * 3584;
    ushort* const acth = actw;             // [16][72] hi plane (pitch 72 = 144B, aligned)
    ushort* const actl = actw + 1152;      // lo plane

    // D-frag -> act planes (in-wave DS ordering; buffers wave-private, no barrier needed)
    #pragma unroll
    for (int reg = 0; reg < 4; ++reg) {
      const int row = lg * 4 + reg;
      #pragma unroll
      for (int nb = 0; nb < 4; ++nb) {
        const float v = acc[nb][reg];
        const ushort h = f2bf(v);
        acth[row * 72 + nb * 16 + l15] = h;
        actl[row * 72 + nb * 16 + l15] = f2bf(v - bf2f(h));
      }
    }

    float y[4][4];
    #pragma unroll
    for (int layer = 0; layer < 4; ++layer) {
      const short8 a0h = *reinterpret_cast<const short8*>(&acth[l15 * 72 + lg * 8]);
      const short8 a1h = *reinterpret_cast<const short8*>(&acth[l15 * 72 + 32 + lg * 8]);
      const short8 a0l = *reinterpret_cast<const short8*>(&actl[l15 * 72 + lg * 8]);
      const short8 a1l = *reinterpret_cast<const short8*>(&actl[l15 * 72 + 32 + lg * 8]);

      f32x4 z[4];
      #pragma unroll
      for (int nb = 0; nb < 4; ++nb) {
        const int co = nb * 16 + l15;
        const short8 b0h = *reinterpret_cast<const short8*>(&wt[wtoff(0, layer, co, lg)]);
        const short8 b1h = *reinterpret_cast<const short8*>(&wt[wtoff(0, layer, co, 4 + lg)]);
        const short8 b0l = *reinterpret_cast<const short8*>(&wt[wtoff(1, layer, co, lg)]);
        const short8 b1l = *reinterpret_cast<const short8*>(&wt[wtoff(1, layer, co, 4 + lg)]);
        z[nb] = {0.f, 0.f, 0.f, 0.f};
        z[nb] = __builtin_amdgcn_mfma_f32_16x16x32_bf16(a0h, b0h, z[nb], 0, 0, 0);
        z[nb] = __builtin_amdgcn_mfma_f32_16x16x32_bf16(a1h, b1h, z[nb], 0, 0, 0);
        z[nb] = __builtin_amdgcn_mfma_f32_16x16x32_bf16(a0h, b0l, z[nb], 0, 0, 0);
        z[nb] = __builtin_amdgcn_mfma_f32_16x16x32_bf16(a1h, b1l, z[nb], 0, 0, 0);
        z[nb] = __builtin_amdgcn_mfma_f32_16x16x32_bf16(a0l, b0h, z[nb], 0, 0, 0);
        z[nb] = __builtin_amdgcn_mfma_f32_16x16x32_bf16(a1l, b1h, z[nb], 0, 0, 0);
      }

      // bias + relu + LayerNorm (channel groups live on l15; reduce via shfl_xor)
      #pragma unroll
      for (int reg = 0; reg < 4; ++reg) {
        float s = 0.f, ss = 0.f;
        #pragma unroll
        for (int nb = 0; nb < 4; ++nb) {
          float v = z[nb][reg] + bias[layer][nb];
          v = fmaxf(v, 0.f);
          y[reg][nb] = v;
          s += v; ss += v * v;
        }
        #pragma unroll
        for (int m = 1; m <= 8; m <<= 1) { s += __shfl_xor(s, m, 64); ss += __shfl_xor(ss, m, 64); }
        const float mu = s * 0.015625f;
        const float var = ss * 0.015625f - mu * mu;
        const float rstd = rsqrtf(var + 1e-6f);
        #pragma unroll
        for (int nb = 0; nb < 4; ++nb)
          y[reg][nb] = (y[reg][nb] - mu) * rstd * sc[layer][nb] + lbv[layer][nb];
      }

      if (layer < 3) {
        #pragma unroll
        for (int reg = 0; reg < 4; ++reg) {
          const int row = lg * 4 + reg;
          #pragma unroll
          for (int nb = 0; nb < 4; ++nb) {
            const float v = y[reg][nb];
            const ushort h = f2bf(v);
            acth[row * 72 + nb * 16 + l15] = h;
            actl[row * 72 + nb * 16 + l15] = f2bf(v - bf2f(h));
          }
        }
      }
    }

    // ---- final stores: x0 (f32) + head out = y @ w_out + b_out ----
    #pragma unroll
    for (int reg = 0; reg < 4; ++reg) {
      const int pl = w * 16 + lg * 4 + reg;
      const size_t gpx = (size_t)(ti + (pl >> 3)) * WW + (tj + (pl & 7));
      #pragma unroll
      for (int nb = 0; nb < 4; ++nb)
        x0_out[(gpx << 6) + nb * 16 + l15] = y[reg][nb];
      float part = y[reg][0] * wo[0] + y[reg][1] * wo[1] + y[reg][2] * wo[2] + y[reg][3] * wo[3];
      #pragma unroll
      for (int m = 1; m <= 8; m <<= 1) part += __shfl_xor(part, m, 64);
      if (l15 == 0) out1[gpx] = part + b0s;
    }
  }
}

extern "C" void kernel_launch(void* const* d_in, const int* in_sizes, int n_in,
                              void* d_out, int out_size, void* d_ws, size_t ws_size,
                              hipStream_t stream) {
  const float* x     = (const float*)d_in[0];
  const float* Ws    = (const float*)d_in[1];
  const float* bs    = (const float*)d_in[2];
  const float* lns   = (const float*)d_in[3];
  const float* lnbv  = (const float*)d_in[4];
  const float* w_out = (const float*)d_in[5];
  const float* b_out = (const float*)d_in[6];
  float* x0_out = (float*)d_out;
  float* out1   = x0_out + (size_t)HWPX * CC;

  fused_cell<<<256, 256, 0, stream>>>(x, Ws, bs, lns, lnbv, w_out, b_out, x0_out, out1);
}

// Round 5
// 360.146 us; speedup vs baseline: 1.5200x; 1.5200x over previous
//
#include <hip/hip_runtime.h>
#include <hip/hip_bf16.h>

// CellAnnotator, R5: two-kernel pipeline, R4-identical numerics (full hi/lo bf16 splitting),
// restructured for occupancy.
//   K1 att: per 8x8 tile, out[64px,64ch] = M[64,K]@X[K,64] with k-space [15][16] padded to 256
//           (no div/mod, no fixup). 3 passes: Mh@Xh + Mh@Xl + Ml@Xh. 64KB LDS -> 2 blocks/CU.
//           att stored as packed (hi<<16|lo) bf16-pair uints.
//   K2 mlp: persistent 512-thread blocks, wt hi/lo in LDS (64KB), wave-private act scratch,
//           6-term hi/lo MFMA per layer + LN + head. May run in-place over the att region.

#define HH 768
#define WW 768
#define HWPX (HH*WW)

typedef __attribute__((ext_vector_type(8))) short short8;
typedef __attribute__((ext_vector_type(4))) float f32x4;

__device__ __forceinline__ ushort f2bf(float f) {
  union { float f; uint u; } c; c.f = f;
  uint u = c.u;
  uint r = u + 0x7fffu + ((u >> 16) & 1u);   // round-to-nearest-even
  return (ushort)(r >> 16);
}
__device__ __forceinline__ float bf2f(ushort h) {
  union { uint u; float f; } c; c.u = ((uint)h) << 16;
  return c.f;
}
__device__ __forceinline__ float sigmoidf(float v) { return 1.f / (1.f + __expf(-v)); }

// Row pitch 256 ushorts (512B). XOR-swizzle the low-3 bits of the 8-elem group index by
// row&7: bijective over 32 groups, 2-way (free) bank pattern on quarter-wave b128 frag reads.
__device__ __forceinline__ int goff(int row, int g) {
  return (row << 8) + (((g & ~7) | ((g ^ row) & 7)) << 3);
}
__device__ __forceinline__ int eoff(int row, int k) {   // per-element (scatter writes)
  const int g = k >> 3;
  return (row << 8) + (((g & ~7) | ((g ^ row) & 7)) << 3) + (k & 7);
}

// ---------------- K1: att ----------------
__global__ __launch_bounds__(256, 2)
void att_k1(const float* __restrict__ x, uint* attp) {
  __shared__ __align__(16) ushort Mb[64 * 256];   // 32 KB  M[px][k] (hi, then lo)
  __shared__ __align__(16) ushort Xb[64 * 256];   // 32 KB  X^T[ch][k] (hi, then lo)
  const int tid = threadIdx.x;
  const int lane = tid & 63, w = tid >> 6;
  const int l15 = lane & 15, lg = lane >> 4;

  // one-time init: zero all of M (scatter slot-set is tile-invariant -> zeros persist),
  // zero X k-groups 30,31 (k in [240,256) never staged; M is zero there but avoid NaN*0).
  {
    const short8 z8 = {0,0,0,0,0,0,0,0};
    #pragma unroll
    for (int i = 0; i < 8; ++i)
      *reinterpret_cast<short8*>(&Mb[(tid + i * 256) * 8]) = z8;
    if (tid < 128) {
      const int row = tid >> 1, g = 30 + (tid & 1);
      *reinterpret_cast<short8*>(&Xb[goff(row, g)]) = z8;
    }
  }

  const int b = blockIdx.x;
  const int tbase = (b & 7) * 1152 + (b >> 3) * 18;   // XCD-chunked contiguous tile bands
  const int p  = tid >> 2;                 // scatter pixel 0..63
  const int pr = p >> 3, pc = p & 7;
  const int cb = (tid & 3) << 4;           // this thread's 16 channels of pixel p
  const int arow = w * 16 + l15;           // A-frag row (output pixel index in tile)

  for (int t18 = 0; t18 < 18; ++t18) {
    const int tile = tbase + t18;
    const int ti = (tile / 96) * 8, tj = (tile % 96) * 8;

    __syncthreads();                       // S0: prev tile's P2 X-reads done

    // center loads + sigmoid, hi/lo retained in regs
    ushort svh[16], svl[16];
    {
      const float* cp = x + ((size_t)((ti + pr) * WW + (tj + pc)) << 6) + cb;
      #pragma unroll
      for (int qd = 0; qd < 4; ++qd) {
        const float4 v = *reinterpret_cast<const float4*>(cp + qd * 4);
        const float vs[4] = {v.x, v.y, v.z, v.w};
        #pragma unroll
        for (int j = 0; j < 4; ++j) {
          const float s = sigmoidf(vs[j]);
          const ushort h = f2bf(s);
          svh[qd * 4 + j] = h;
          svl[qd * 4 + j] = f2bf(s - bf2f(h));
        }
      }
    }
    // scatter M hi: k = (pr+di)*16 + (pc+dj), di=ch>>3, dj=ch&7 (no carry: pc+dj<=14)
    #pragma unroll
    for (int j = 0; j < 16; ++j) {
      const int ch = cb + j;
      const int k = ((pr + (ch >> 3)) << 4) | (pc + (ch & 7));
      Mb[eoff(p, k)] = svh[j];
    }
    // stage X^T hi (lane = channel); keep lo in regs for later overwrite
    short8 l8s[8];
    #pragma unroll
    for (int t = 0; t < 8; ++t) {
      const int g = w + 4 * t;             // k-group; waves 2,3 skip g=30,31
      if (g < 30) {
        const int r = g >> 1, c0 = (g & 1) << 3;
        const int gr = ti + r - 3;
        const bool rok = (unsigned)gr < (unsigned)HH;
        float vv[8];
        #pragma unroll
        for (int s = 0; s < 8; ++s) {
          const int c = c0 + s;
          const int gc = tj + c - 3;
          vv[s] = (rok && c < 15 && (unsigned)gc < (unsigned)WW)
                      ? x[((size_t)(gr * WW + gc) << 6) + lane] : 0.f;
        }
        short8 h8, lo8;
        #pragma unroll
        for (int s = 0; s < 8; ++s) {
          const ushort h = f2bf(vv[s]);
          h8[s] = (short)h;
          lo8[s] = (short)f2bf(vv[s] - bf2f(h));
        }
        l8s[t] = lo8;
        *reinterpret_cast<short8*>(&Xb[goff(lane, g)]) = h8;
      }
    }
    __syncthreads();                       // S1: Mhi + Xh visible

    // P1: Mh@Xh (save A-frags)
    short8 afr[8];
    f32x4 acc[4];
    #pragma unroll
    for (int nb = 0; nb < 4; ++nb) acc[nb] = {0.f, 0.f, 0.f, 0.f};
    #pragma unroll
    for (int ks = 0; ks < 8; ++ks) {
      const int g = ks * 4 + lg;
      afr[ks] = *reinterpret_cast<const short8*>(&Mb[goff(arow, g)]);
      #pragma unroll
      for (int nb = 0; nb < 4; ++nb) {
        const short8 bb = *reinterpret_cast<const short8*>(&Xb[goff(nb * 16 + l15, g)]);
        acc[nb] = __builtin_amdgcn_mfma_f32_16x16x32_bf16(afr[ks], bb, acc[nb], 0, 0, 0);
      }
    }
    __syncthreads();                       // S2: P1 M-reads done

    // scatter M lo (same slots)
    #pragma unroll
    for (int j = 0; j < 16; ++j) {
      const int ch = cb + j;
      const int k = ((pr + (ch >> 3)) << 4) | (pc + (ch & 7));
      Mb[eoff(p, k)] = svl[j];
    }
    __syncthreads();                       // S3: Mlo visible

    // P3: Ml@Xh
    #pragma unroll
    for (int ks = 0; ks < 8; ++ks) {
      const int g = ks * 4 + lg;
      const short8 a = *reinterpret_cast<const short8*>(&Mb[goff(arow, g)]);
      #pragma unroll
      for (int nb = 0; nb < 4; ++nb) {
        const short8 bb = *reinterpret_cast<const short8*>(&Xb[goff(nb * 16 + l15, g)]);
        acc[nb] = __builtin_amdgcn_mfma_f32_16x16x32_bf16(a, bb, acc[nb], 0, 0, 0);
      }
    }
    __syncthreads();                       // S4: all Xh reads done

    // overwrite X with lo (from regs)
    #pragma unroll
    for (int t = 0; t < 8; ++t) {
      const int g = w + 4 * t;
      if (g < 30)
        *reinterpret_cast<short8*>(&Xb[goff(lane, g)]) = l8s[t];
    }
    __syncthreads();                       // S5: Xl visible

    // P2: Mh(saved)@Xl
    #pragma unroll
    for (int ks = 0; ks < 8; ++ks) {
      const int g = ks * 4 + lg;
      #pragma unroll
      for (int nb = 0; nb < 4; ++nb) {
        const short8 bb = *reinterpret_cast<const short8*>(&Xb[goff(nb * 16 + l15, g)]);
        acc[nb] = __builtin_amdgcn_mfma_f32_16x16x32_bf16(afr[ks], bb, acc[nb], 0, 0, 0);
      }
    }

    // store att as packed (hi<<16 | lo)
    #pragma unroll
    for (int reg = 0; reg < 4; ++reg) {
      const int pl = w * 16 + lg * 4 + reg;
      const size_t gpx = (size_t)(ti + (pl >> 3)) * WW + (tj + (pl & 7));
      #pragma unroll
      for (int nb = 0; nb < 4; ++nb) {
        const float v = acc[nb][reg];
        const ushort h = f2bf(v);
        const ushort lo = f2bf(v - bf2f(h));
        attp[(gpx << 6) + nb * 16 + l15] = ((uint)h << 16) | (uint)lo;
      }
    }
  }
}

// ---------------- K2: MLP + LN + head (persistent, 512 threads) ----------------
__global__ __launch_bounds__(512, 2)
void mlp_k2(const float* attf, const float* __restrict__ Ws,
            const float* __restrict__ bs, const float* __restrict__ lns,
            const float* __restrict__ lnb, const float* __restrict__ w_out,
            const float* __restrict__ b_out, float* x0_out,
            float* __restrict__ out1) {
  __shared__ __align__(16) ushort wt[2 * 4 * 64 * 64];   // 64 KB [plane][layer][co][ci swz]
  __shared__ __align__(16) ushort act[8 * 2304];         // 36 KB wave-private hi/lo act
  const int tid = threadIdx.x;
  const int lane = tid & 63, wid = tid >> 6;
  const int l15 = lane & 15, lg = lane >> 4;

  // stage wt hi/lo (thread = half a (layer,co) row)
  {
    const int row = tid >> 1;               // (layer<<6)|co
    const int l = row >> 6, co = row & 63;
    const int ci0 = (tid & 1) << 5;
    const int base = row << 6;
    for (int q = 0; q < 32; ++q) {
      const int ci = ci0 + q;
      const float v = Ws[(((l << 6) + ci) << 6) + co];
      const int e = ((((ci >> 3) ^ co) & 7) << 3) | (ci & 7);
      const ushort h = f2bf(v);
      wt[base + e] = h;
      wt[16384 + base + e] = f2bf(v - bf2f(h));
    }
  }
  // hoist per-lane params
  float bias[4][4], sc[4][4], lbv[4][4];
  #pragma unroll
  for (int L = 0; L < 4; ++L)
    #pragma unroll
    for (int nb = 0; nb < 4; ++nb) {
      const int ch = (L << 6) + nb * 16 + l15;
      bias[L][nb] = bs[ch]; sc[L][nb] = lns[ch]; lbv[L][nb] = lnb[ch];
    }
  float wo[4];
  #pragma unroll
  for (int nb = 0; nb < 4; ++nb) wo[nb] = w_out[nb * 16 + l15];
  const float b0s = b_out[0];
  __syncthreads();

  ushort* const acth = act + wid * 2304;   // [16][72] hi
  ushort* const actl = acth + 1152;        // [16][72] lo

  for (int it = 0; it < 18; ++it) {
    const int chunk = blockIdx.x + (it << 8);      // 256 blocks x 18 iters = 4608 chunks
    const int px_base = chunk * 128 + wid * 16;

    // layer-0 A-frags from packed att (float-typed loads: att region may alias x0_out)
    const float* ap = attf + ((size_t)(px_base + l15) << 6) + lg * 8;
    uint ua[8], ub[8];
    {
      const float4 f0 = *reinterpret_cast<const float4*>(ap);
      const float4 f1 = *reinterpret_cast<const float4*>(ap + 4);
      const float4 f2 = *reinterpret_cast<const float4*>(ap + 32);
      const float4 f3 = *reinterpret_cast<const float4*>(ap + 36);
      ua[0]=__float_as_uint(f0.x); ua[1]=__float_as_uint(f0.y); ua[2]=__float_as_uint(f0.z); ua[3]=__float_as_uint(f0.w);
      ua[4]=__float_as_uint(f1.x); ua[5]=__float_as_uint(f1.y); ua[6]=__float_as_uint(f1.z); ua[7]=__float_as_uint(f1.w);
      ub[0]=__float_as_uint(f2.x); ub[1]=__float_as_uint(f2.y); ub[2]=__float_as_uint(f2.z); ub[3]=__float_as_uint(f2.w);
      ub[4]=__float_as_uint(f3.x); ub[5]=__float_as_uint(f3.y); ub[6]=__float_as_uint(f3.z); ub[7]=__float_as_uint(f3.w);
    }
    short8 a0h, a0l, a1h, a1l;
    #pragma unroll
    for (int s = 0; s < 8; ++s) {
      a0h[s] = (short)(ua[s] >> 16);  a0l[s] = (short)(ua[s] & 0xffffu);
      a1h[s] = (short)(ub[s] >> 16);  a1l[s] = (short)(ub[s] & 0xffffu);
    }

    float y[4][4];
    #pragma unroll
    for (int layer = 0; layer < 4; ++layer) {
      if (layer > 0) {
        a0h = *reinterpret_cast<const short8*>(&acth[l15 * 72 + lg * 8]);
        a1h = *reinterpret_cast<const short8*>(&acth[l15 * 72 + 32 + lg * 8]);
        a0l = *reinterpret_cast<const short8*>(&actl[l15 * 72 + lg * 8]);
        a1l = *reinterpret_cast<const short8*>(&actl[l15 * 72 + 32 + lg * 8]);
      }
      f32x4 z[4];
      #pragma unroll
      for (int nb = 0; nb < 4; ++nb) {
        const int co = nb * 16 + l15;
        const int wb = ((layer << 6) + co) << 6;
        const int e0 = (((lg    ) ^ co) & 7) << 3;
        const int e1 = (((lg + 4) ^ co) & 7) << 3;
        const short8 b0h = *reinterpret_cast<const short8*>(&wt[wb + e0]);
        const short8 b1h = *reinterpret_cast<const short8*>(&wt[wb + e1]);
        const short8 b0l = *reinterpret_cast<const short8*>(&wt[16384 + wb + e0]);
        const short8 b1l = *reinterpret_cast<const short8*>(&wt[16384 + wb + e1]);
        z[nb] = {0.f, 0.f, 0.f, 0.f};
        z[nb] = __builtin_amdgcn_mfma_f32_16x16x32_bf16(a0h, b0h, z[nb], 0, 0, 0);
        z[nb] = __builtin_amdgcn_mfma_f32_16x16x32_bf16(a1h, b1h, z[nb], 0, 0, 0);
        z[nb] = __builtin_amdgcn_mfma_f32_16x16x32_bf16(a0h, b0l, z[nb], 0, 0, 0);
        z[nb] = __builtin_amdgcn_mfma_f32_16x16x32_bf16(a1h, b1l, z[nb], 0, 0, 0);
        z[nb] = __builtin_amdgcn_mfma_f32_16x16x32_bf16(a0l, b0h, z[nb], 0, 0, 0);
        z[nb] = __builtin_amdgcn_mfma_f32_16x16x32_bf16(a1l, b1h, z[nb], 0, 0, 0);
      }
      // bias + relu + LayerNorm
      #pragma unroll
      for (int reg = 0; reg < 4; ++reg) {
        float s = 0.f, ss = 0.f;
        #pragma unroll
        for (int nb = 0; nb < 4; ++nb) {
          float v = z[nb][reg] + bias[layer][nb];
          v = fmaxf(v, 0.f);
          y[reg][nb] = v;
          s += v; ss += v * v;
        }
        #pragma unroll
        for (int m = 1; m <= 8; m <<= 1) { s += __shfl_xor(s, m, 64); ss += __shfl_xor(ss, m, 64); }
        const float mu = s * 0.015625f;
        const float var = ss * 0.015625f - mu * mu;
        const float rstd = rsqrtf(var + 1e-6f);
        #pragma unroll
        for (int nb = 0; nb < 4; ++nb)
          y[reg][nb] = (y[reg][nb] - mu) * rstd * sc[layer][nb] + lbv[layer][nb];
      }
      if (layer < 3) {
        #pragma unroll
        for (int reg = 0; reg < 4; ++reg) {
          const int row = lg * 4 + reg;
          #pragma unroll
          for (int nb = 0; nb < 4; ++nb) {
            const float v = y[reg][nb];
            const ushort h = f2bf(v);
            acth[row * 72 + nb * 16 + l15] = h;
            actl[row * 72 + nb * 16 + l15] = f2bf(v - bf2f(h));
          }
        }
      }
    }

    // final stores: x0 f32 (overwrites this block's own att slots) + head
    #pragma unroll
    for (int reg = 0; reg < 4; ++reg) {
      const size_t pxg = (size_t)px_base + lg * 4 + reg;
      #pragma unroll
      for (int nb = 0; nb < 4; ++nb)
        x0_out[(pxg << 6) + nb * 16 + l15] = y[reg][nb];
      float part = y[reg][0] * wo[0] + y[reg][1] * wo[1] + y[reg][2] * wo[2] + y[reg][3] * wo[3];
      #pragma unroll
      for (int m = 1; m <= 8; m <<= 1) part += __shfl_xor(part, m, 64);
      if (l15 == 0) out1[pxg] = part + b0s;
    }
  }
}

extern "C" void kernel_launch(void* const* d_in, const int* in_sizes, int n_in,
                              void* d_out, int out_size, void* d_ws, size_t ws_size,
                              hipStream_t stream) {
  const float* x     = (const float*)d_in[0];
  const float* Ws    = (const float*)d_in[1];
  const float* bs    = (const float*)d_in[2];
  const float* lns   = (const float*)d_in[3];
  const float* lnbv  = (const float*)d_in[4];
  const float* w_out = (const float*)d_in[5];
  const float* b_out = (const float*)d_in[6];
  float* x0_out = (float*)d_out;
  float* out1   = x0_out + (size_t)HWPX * 64;

  // att buffer: use workspace if large enough, else in-place over the x0 output region
  // (block-private read-before-write in K2; K1 rewrites it every launch -> replay-safe).
  uint* attbuf = (ws_size >= (size_t)HWPX * 64 * sizeof(uint))
                     ? (uint*)d_ws : (uint*)d_out;

  att_k1<<<512, 256, 0, stream>>>(x, attbuf);
  mlp_k2<<<256, 512, 0, stream>>>((const float*)attbuf, Ws, bs, lns, lnbv,
                                  w_out, b_out, x0_out, out1);
}